// Round 8
// baseline (153.855 us; speedup 1.0000x reference)
//
#include <hip/hip_runtime.h>
#include <hip/hip_cooperative_groups.h>

namespace cg = cooperative_groups;

// N=256, A=1024, B=128, C=16
//   act = inp @ theta.reshape(1024, 2048)            (bf16 MFMA, split-K=2)
//   d[i,j,b] = sum_c |act[j,b,c] - act[i,b,c]|
//   mb[j,b]  = (sum_i exp(-d[i,j,b]) - 1) / 255
//   out = concat([inp, mb], axis=1)                  [256, 1152] fp32
//
// ONE cooperative kernel, 512 blocks (2/CU, 2 waves/SIMD), 256 threads.
// Phase 1 = round-6 pipelined MFMA GEMM (identical structure).
// grid.sync()
// Phase 2 = pairwise exp(-L1) with fp16-packed C dimension.

#define NN 256
#define AA 1024
#define CC 16
#define NBB 2048       // B*C
#define OUTW 1152      // A + B
#define PHALF_E (128 * 256 * 16)   // elements per split-K partial (bf16)

typedef __attribute__((ext_vector_type(4))) float f32x4;
typedef __attribute__((ext_vector_type(8))) short bf16x8;
typedef __attribute__((ext_vector_type(4))) unsigned int u32x4;
typedef __attribute__((ext_vector_type(8))) unsigned short u16x8;
typedef _Float16 f16x2 __attribute__((ext_vector_type(2)));
typedef __fp16 fp16x2_raw __attribute__((ext_vector_type(2)));   // cvt_pkrtz return type

// pack two fp32 -> two bf16 (truncation) in ONE v_perm_b32.
__device__ __forceinline__ unsigned int pack_bf2(float lo, float hi) {
    union { float f; unsigned u; } a, b;
    a.f = lo; b.f = hi;
    return __builtin_amdgcn_perm(b.u, a.u, 0x07060302u);
}

// pack two fp32 -> two fp16 (RTZ) as a u32 via v_cvt_pkrtz_f16_f32.
__device__ __forceinline__ unsigned int pack_f16_2(float lo, float hi) {
    union { fp16x2_raw h; unsigned u; } cv;
    cv.h = __builtin_amdgcn_cvt_pkrtz(lo, hi);
    return cv.u;
}

__device__ __forceinline__ unsigned short f2bf_trunc(float x) {
    union { float f; unsigned u; } v; v.f = x;
    return (unsigned short)(v.u >> 16);
}

__device__ __forceinline__ float bf2f(unsigned short h) {
    union { unsigned u; float f; } v; v.u = ((unsigned)h) << 16;
    return v.f;
}

// barrier that does NOT drain vmcnt (LDS visibility only) — prefetch global
// loads stay in flight across it.
__device__ __forceinline__ void barrier_keep_loads() {
    asm volatile("s_waitcnt lgkmcnt(0)" ::: "memory");
    __builtin_amdgcn_s_barrier();
    __builtin_amdgcn_sched_barrier(0);
}

__global__ __launch_bounds__(256) void fused_kernel(const float* __restrict__ inp,
                                                    const float* __restrict__ theta,
                                                    unsigned short* __restrict__ part,
                                                    float* __restrict__ out) {
    __shared__ __align__(16) char smem[24576];
    const int tid = threadIdx.x;
    const int g = blockIdx.x;        // 0..511

    // ======================= phase 1: GEMM =================================
    {
        const int lane = tid & 63;
        const int w = tid >> 6;
        const int wn = w & 1, wm = w >> 1;
        const int bn = g & 31, bm = (g >> 5) & 7, ks = g >> 8;
        const int col0 = bn * 64, row0 = bm * 32, kbase = ks * 512;

        char* const AsB[2] = { smem, smem + 4096 };            // [m][k] bf16
        char* const BsB[2] = { smem + 8192, smem + 16384 };    // [n][k] bf16

        const int am = tid >> 3, ach = tid & 7;     // A stage: row, 16B chunk
        const int nb = tid & 63, kq = tid >> 6;     // B stage: n row, k quarter

        const float* const abase = inp + (row0 + am) * AA + kbase + ach * 8;
        const float* const bbase = theta + (kbase + kq * 16) * NBB + col0 + nb;

        f32x4 a0[2], a1[2];
        float bv[2][16];

        #pragma unroll
        for (int s = 0; s < 2; ++s) {
            const float* asrc = abase + s * 64;
            a0[s] = *(const f32x4*)asrc; a1[s] = *(const f32x4*)(asrc + 4);
            const float* bsrc = bbase + (size_t)s * 64 * NBB;
            #pragma unroll
            for (int u = 0; u < 16; ++u) bv[s][u] = bsrc[u * NBB];
        }

        f32x4 acc[2] = {};

        #pragma unroll
        for (int kt = 0; kt < 8; ++kt) {
            if (kt == 0) {
                char* Asb = AsB[0]; char* Bsb = BsB[0];
                u32x4 ha;
                ha.x = pack_bf2(a0[0].x, a0[0].y); ha.y = pack_bf2(a0[0].z, a0[0].w);
                ha.z = pack_bf2(a1[0].x, a1[0].y); ha.w = pack_bf2(a1[0].z, a1[0].w);
                *(u32x4*)(Asb + ((am * 128 + ach * 16) ^ ((am & 7) << 4))) = ha;
                u32x4 hb0, hb1;
                hb0.x = pack_bf2(bv[0][0], bv[0][1]);   hb0.y = pack_bf2(bv[0][2], bv[0][3]);
                hb0.z = pack_bf2(bv[0][4], bv[0][5]);   hb0.w = pack_bf2(bv[0][6], bv[0][7]);
                hb1.x = pack_bf2(bv[0][8], bv[0][9]);   hb1.y = pack_bf2(bv[0][10], bv[0][11]);
                hb1.z = pack_bf2(bv[0][12], bv[0][13]); hb1.w = pack_bf2(bv[0][14], bv[0][15]);
                const int bb = nb * 128 + kq * 32, swz = (nb & 7) << 4;
                *(u32x4*)(Bsb + (bb ^ swz)) = hb0;
                *(u32x4*)(Bsb + ((bb + 16) ^ swz)) = hb1;
                barrier_keep_loads();
            }
            if (kt < 6) {
                const int s = kt & 1;
                const float* asrc = abase + (kt + 2) * 64;
                a0[s] = *(const f32x4*)asrc; a1[s] = *(const f32x4*)(asrc + 4);
                const float* bsrc = bbase + (size_t)(kt + 2) * 64 * NBB;
                #pragma unroll
                for (int u = 0; u < 16; ++u) bv[s][u] = bsrc[u * NBB];
            }
            {
                char* Asb = AsB[kt & 1]; char* Bsb = BsB[kt & 1];
                #pragma unroll
                for (int ks2 = 0; ks2 < 2; ++ks2) {
                    const int kbyte = ks2 * 64 + (lane >> 4) * 16;
                    const int m = wm * 16 + (lane & 15);
                    const bf16x8 af = *(bf16x8*)(Asb + ((m * 128 + kbyte) ^ ((m & 7) << 4)));
                    #pragma unroll
                    for (int nf = 0; nf < 2; ++nf) {
                        const int n = wn * 32 + nf * 16 + (lane & 15);
                        const bf16x8 bfv = *(bf16x8*)(Bsb + ((n * 128 + kbyte) ^ ((n & 7) << 4)));
                        acc[nf] = __builtin_amdgcn_mfma_f32_16x16x32_bf16(af, bfv, acc[nf], 0, 0, 0);
                    }
                }
            }
            if (kt < 7) {
                const int s = (kt + 1) & 1;
                char* Asb = AsB[s]; char* Bsb = BsB[s];
                u32x4 ha;
                ha.x = pack_bf2(a0[s].x, a0[s].y); ha.y = pack_bf2(a0[s].z, a0[s].w);
                ha.z = pack_bf2(a1[s].x, a1[s].y); ha.w = pack_bf2(a1[s].z, a1[s].w);
                *(u32x4*)(Asb + ((am * 128 + ach * 16) ^ ((am & 7) << 4))) = ha;
                u32x4 hb0, hb1;
                hb0.x = pack_bf2(bv[s][0], bv[s][1]);   hb0.y = pack_bf2(bv[s][2], bv[s][3]);
                hb0.z = pack_bf2(bv[s][4], bv[s][5]);   hb0.w = pack_bf2(bv[s][6], bv[s][7]);
                hb1.x = pack_bf2(bv[s][8], bv[s][9]);   hb1.y = pack_bf2(bv[s][10], bv[s][11]);
                hb1.z = pack_bf2(bv[s][12], bv[s][13]); hb1.w = pack_bf2(bv[s][14], bv[s][15]);
                const int bb = nb * 128 + kq * 32, swz = (nb & 7) << 4;
                *(u32x4*)(Bsb + (bb ^ swz)) = hb0;
                *(u32x4*)(Bsb + ((bb + 16) ^ swz)) = hb1;
                barrier_keep_loads();
            }
        }

        // epilogue: bf16 partial [ks][b][i][c]; C/D: col=lane&15, row=(lane>>4)*4+r
        unsigned short* p = part + (size_t)ks * PHALF_E;
        #pragma unroll
        for (int nf = 0; nf < 2; ++nf) {
            const int col = col0 + wn * 32 + nf * 16 + (lane & 15);
            const int bcol = col >> 4, c = col & 15;
            #pragma unroll
            for (int r = 0; r < 4; ++r) {
                const int row = row0 + wm * 16 + (lane >> 4) * 4 + r;
                p[bcol * (NN * CC) + row * CC + c] = f2bf_trunc(acc[nf][r]);
            }
        }
        // fused copy (ks==0 blocks): 32x32 patch of inp -> out[:, :1024]
        if (ks == 0) {
            const int mr = row0 + (tid >> 3);
            const int c = bn * 32 + (tid & 7) * 4;
            *(f32x4*)(out + mr * OUTW + c) = *(const f32x4*)(inp + mr * AA + c);
        }
    }

    __threadfence();
    cg::this_grid().sync();

    // ======================= phase 2: pairwise ==============================
    {
        const int b = g >> 2;        // 0..127
        const int jq = g & 3;        // 0..3

        const unsigned short* p0 = part + (size_t)b * (NN * CC);
        const unsigned short* p1 = p0 + PHALF_E;

        // stage row tid as 16 fp16 (32 B), row stride 48 B (16B-aligned, <=2-way banks)
        {
            const u16x8 x0a = *(const u16x8*)(p0 + tid * CC);
            const u16x8 x0b = *(const u16x8*)(p0 + tid * CC + 8);
            const u16x8 x1a = *(const u16x8*)(p1 + tid * CC);
            const u16x8 x1b = *(const u16x8*)(p1 + tid * CC + 8);
            float t[16];
            #pragma unroll
            for (int e = 0; e < 8; ++e) {
                t[e] = bf2f(x0a[e]) + bf2f(x1a[e]);
                t[8 + e] = bf2f(x0b[e]) + bf2f(x1b[e]);
            }
            u32x4 w0, w1;
            w0.x = pack_f16_2(t[0], t[1]);
            w0.y = pack_f16_2(t[2], t[3]);
            w0.z = pack_f16_2(t[4], t[5]);
            w0.w = pack_f16_2(t[6], t[7]);
            w1.x = pack_f16_2(t[8], t[9]);
            w1.y = pack_f16_2(t[10], t[11]);
            w1.z = pack_f16_2(t[12], t[13]);
            w1.w = pack_f16_2(t[14], t[15]);
            char* dst = smem + tid * 48;
            *(u32x4*)dst = w0;
            *(u32x4*)(dst + 16) = w1;
        }
        __syncthreads();

        const int jg = tid >> 4;     // 0..15
        const int q = tid & 15;      // 0..15
        const int j0 = jq * 64 + jg * 4;

        union U { u32x4 v; f16x2 h[4]; };
        f16x2 ar[4][8];
        #pragma unroll
        for (int jj = 0; jj < 4; ++jj) {
            U ra, rb;
            ra.v = *(const u32x4*)(smem + (j0 + jj) * 48);
            rb.v = *(const u32x4*)(smem + (j0 + jj) * 48 + 16);
            #pragma unroll
            for (int h = 0; h < 4; ++h) { ar[jj][h] = ra.h[h]; ar[jj][4 + h] = rb.h[h]; }
        }

        float s[4] = {0.f, 0.f, 0.f, 0.f};
        #pragma unroll 4
        for (int ii = 0; ii < 16; ++ii) {
            const char* rp = smem + (ii * 16 + q) * 48;
            U ra, rb;
            ra.v = *(const u32x4*)rp;
            rb.v = *(const u32x4*)(rp + 16);
            f16x2 rv[8];
            #pragma unroll
            for (int h = 0; h < 4; ++h) { rv[h] = ra.h[h]; rv[4 + h] = rb.h[h]; }
            #pragma unroll
            for (int jj = 0; jj < 4; ++jj) {
                f16x2 d2 = { (_Float16)0.f, (_Float16)0.f };
                #pragma unroll
                for (int h = 0; h < 8; ++h) {
                    union { f16x2 hh; unsigned u; } tt;
                    tt.hh = rv[h] - ar[jj][h];
                    tt.u &= 0x7FFF7FFFu;        // packed abs
                    d2 += tt.hh;
                }
                const float d = (float)d2.x + (float)d2.y;
                s[jj] += __expf(-d);
            }
        }
        #pragma unroll
        for (int jj = 0; jj < 4; ++jj) {
            s[jj] += __shfl_xor(s[jj], 1);
            s[jj] += __shfl_xor(s[jj], 2);
            s[jj] += __shfl_xor(s[jj], 4);
            s[jj] += __shfl_xor(s[jj], 8);
        }
        if (q == 0) {
            #pragma unroll
            for (int jj = 0; jj < 4; ++jj)
                out[(j0 + jj) * OUTW + AA + b] = (s[jj] - 1.0f) * (1.0f / 255.0f);
        }
    }
}

extern "C" void kernel_launch(void* const* d_in, const int* in_sizes, int n_in,
                              void* d_out, int out_size, void* d_ws, size_t ws_size,
                              hipStream_t stream) {
    const float* inp = (const float*)d_in[0];     // [256][1024]
    const float* theta = (const float*)d_in[1];   // [1024][2048]
    float* out = (float*)d_out;                   // [256][1152]
    unsigned short* part = (unsigned short*)d_ws; // 2 bf16 partials, 2 MiB

    void* args[] = {(void*)&inp, (void*)&theta, (void*)&part, (void*)&out};
    hipLaunchCooperativeKernel((const void*)fused_kernel, dim3(512), dim3(256),
                               args, 0, stream);
}

// Round 9
// 22.821 us; speedup vs baseline: 6.7417x; 6.7417x over previous
//
#include <hip/hip_runtime.h>

// N=256, A=1024, B=128, C=16
//   act = inp @ theta.reshape(1024, 2048)            (bf16 MFMA, split-K=2)
//   d[i,j,b] = sum_c |act[j,b,c] - act[i,b,c]|
//   mb[j,b]  = (sum_i exp(-d[i,j,b]) - 1) / 255
//   out = concat([inp, mb], axis=1)                  [256, 1152] fp32
//
// Two kernels (round-6 structure; cooperative grid.sync measured at ~100 µs
// on this platform in r4/r8 — do not fuse).
// K1: pipelined bf16-MFMA GEMM -> fp16 partials part[ks][b][i][c].
// K2: pairwise exp(-L1), fp16-packed C dimension (validated absmax 0.0 in r8).

#define NN 256
#define AA 1024
#define CC 16
#define NBB 2048       // B*C
#define OUTW 1152      // A + B
#define PHALF_E (128 * 256 * 16)   // elements per split-K partial (fp16)

typedef __attribute__((ext_vector_type(4))) float f32x4;
typedef __attribute__((ext_vector_type(8))) short bf16x8;
typedef __attribute__((ext_vector_type(4))) unsigned int u32x4;
typedef __attribute__((ext_vector_type(8))) unsigned short u16x8;
typedef _Float16 f16x2 __attribute__((ext_vector_type(2)));
typedef __fp16 fp16x2_raw __attribute__((ext_vector_type(2)));   // cvt_pkrtz return type

// pack two fp32 -> two bf16 (truncation) in ONE v_perm_b32.
__device__ __forceinline__ unsigned int pack_bf2(float lo, float hi) {
    union { float f; unsigned u; } a, b;
    a.f = lo; b.f = hi;
    return __builtin_amdgcn_perm(b.u, a.u, 0x07060302u);
}

// pack two fp32 -> two fp16 (RTZ) as u32 via v_cvt_pkrtz_f16_f32.
__device__ __forceinline__ unsigned int pack_f16_2(float lo, float hi) {
    union { fp16x2_raw h; unsigned u; } cv;
    cv.h = __builtin_amdgcn_cvt_pkrtz(lo, hi);
    return cv.u;
}

// barrier that does NOT drain vmcnt (LDS visibility only) — prefetch global
// loads stay in flight across it.
__device__ __forceinline__ void barrier_keep_loads() {
    asm volatile("s_waitcnt lgkmcnt(0)" ::: "memory");
    __builtin_amdgcn_s_barrier();
    __builtin_amdgcn_sched_barrier(0);
}

// ---------------------------------------------------------------------------
// Kernel 1: bf16-MFMA GEMM, tile 32m x 64n, BK=64, split-K=2 (8 ktiles).
// Grid (32 bn, 8 bm, 2 ks) = 512 blocks (2/CU), 256 threads (4 waves, 2x2).
// Double-buffered LDS, one non-draining barrier per ktile, depth-2 register
// prefetch. LDS [m][k]/[n][k] bf16 rows 128 B, XOR swizzle byte^=(row&7)<<4.
// Output: FP16 partials part[ks][b][i][c] (b = col/16).
// ---------------------------------------------------------------------------
__global__ __launch_bounds__(256) void gemm_kernel(const float* __restrict__ inp,
                                                   const float* __restrict__ theta,
                                                   unsigned short* __restrict__ part,
                                                   float* __restrict__ out) {
    const int tid = threadIdx.x;
    const int lane = tid & 63;
    const int w = tid >> 6;
    const int wn = w & 1, wm = w >> 1;
    const int col0 = blockIdx.x * 64;
    const int row0 = blockIdx.y * 32;
    const int ks = blockIdx.z;
    const int kbase = ks * 512;

    __shared__ unsigned short As[2][32 * 64];   // 2 x 4 KiB  [m][k]
    __shared__ unsigned short Bs[2][64 * 64];   // 2 x 8 KiB  [n][k]

    const int am = tid >> 3, ach = tid & 7;     // A stage: row, 16B chunk
    const int nb = tid & 63, kq = tid >> 6;     // B stage: n row, k quarter

    const float* const abase = inp + (row0 + am) * AA + kbase + ach * 8;
    const float* const bbase = theta + (kbase + kq * 16) * NBB + col0 + nb;

    f32x4 a0[2], a1[2];
    float bv[2][16];

    #pragma unroll
    for (int s = 0; s < 2; ++s) {
        const float* asrc = abase + s * 64;
        a0[s] = *(const f32x4*)asrc; a1[s] = *(const f32x4*)(asrc + 4);
        const float* bsrc = bbase + (size_t)s * 64 * NBB;
        #pragma unroll
        for (int u = 0; u < 16; ++u) bv[s][u] = bsrc[u * NBB];
    }

    f32x4 acc[2] = {};

    #pragma unroll
    for (int kt = 0; kt < 8; ++kt) {
        if (kt == 0) {
            char* Asb = (char*)As[0]; char* Bsb = (char*)Bs[0];
            u32x4 ha;
            ha.x = pack_bf2(a0[0].x, a0[0].y); ha.y = pack_bf2(a0[0].z, a0[0].w);
            ha.z = pack_bf2(a1[0].x, a1[0].y); ha.w = pack_bf2(a1[0].z, a1[0].w);
            *(u32x4*)(Asb + ((am * 128 + ach * 16) ^ ((am & 7) << 4))) = ha;
            u32x4 hb0, hb1;
            hb0.x = pack_bf2(bv[0][0], bv[0][1]);   hb0.y = pack_bf2(bv[0][2], bv[0][3]);
            hb0.z = pack_bf2(bv[0][4], bv[0][5]);   hb0.w = pack_bf2(bv[0][6], bv[0][7]);
            hb1.x = pack_bf2(bv[0][8], bv[0][9]);   hb1.y = pack_bf2(bv[0][10], bv[0][11]);
            hb1.z = pack_bf2(bv[0][12], bv[0][13]); hb1.w = pack_bf2(bv[0][14], bv[0][15]);
            const int bb = nb * 128 + kq * 32, swz = (nb & 7) << 4;
            *(u32x4*)(Bsb + (bb ^ swz)) = hb0;
            *(u32x4*)(Bsb + ((bb + 16) ^ swz)) = hb1;
            barrier_keep_loads();
        }
        if (kt < 6) {
            const int s = kt & 1;
            const float* asrc = abase + (kt + 2) * 64;
            a0[s] = *(const f32x4*)asrc; a1[s] = *(const f32x4*)(asrc + 4);
            const float* bsrc = bbase + (size_t)(kt + 2) * 64 * NBB;
            #pragma unroll
            for (int u = 0; u < 16; ++u) bv[s][u] = bsrc[u * NBB];
        }
        {
            char* Asb = (char*)As[kt & 1]; char* Bsb = (char*)Bs[kt & 1];
            #pragma unroll
            for (int ks2 = 0; ks2 < 2; ++ks2) {
                const int kbyte = ks2 * 64 + (lane >> 4) * 16;
                const int m = wm * 16 + (lane & 15);
                const bf16x8 af = *(bf16x8*)(Asb + ((m * 128 + kbyte) ^ ((m & 7) << 4)));
                #pragma unroll
                for (int nf = 0; nf < 2; ++nf) {
                    const int n = wn * 32 + nf * 16 + (lane & 15);
                    const bf16x8 bfv = *(bf16x8*)(Bsb + ((n * 128 + kbyte) ^ ((n & 7) << 4)));
                    acc[nf] = __builtin_amdgcn_mfma_f32_16x16x32_bf16(af, bfv, acc[nf], 0, 0, 0);
                }
            }
        }
        if (kt < 7) {
            const int s = (kt + 1) & 1;
            char* Asb = (char*)As[s]; char* Bsb = (char*)Bs[s];
            u32x4 ha;
            ha.x = pack_bf2(a0[s].x, a0[s].y); ha.y = pack_bf2(a0[s].z, a0[s].w);
            ha.z = pack_bf2(a1[s].x, a1[s].y); ha.w = pack_bf2(a1[s].z, a1[s].w);
            *(u32x4*)(Asb + ((am * 128 + ach * 16) ^ ((am & 7) << 4))) = ha;
            u32x4 hb0, hb1;
            hb0.x = pack_bf2(bv[s][0], bv[s][1]);   hb0.y = pack_bf2(bv[s][2], bv[s][3]);
            hb0.z = pack_bf2(bv[s][4], bv[s][5]);   hb0.w = pack_bf2(bv[s][6], bv[s][7]);
            hb1.x = pack_bf2(bv[s][8], bv[s][9]);   hb1.y = pack_bf2(bv[s][10], bv[s][11]);
            hb1.z = pack_bf2(bv[s][12], bv[s][13]); hb1.w = pack_bf2(bv[s][14], bv[s][15]);
            const int bb = nb * 128 + kq * 32, swz = (nb & 7) << 4;
            *(u32x4*)(Bsb + (bb ^ swz)) = hb0;
            *(u32x4*)(Bsb + ((bb + 16) ^ swz)) = hb1;
            barrier_keep_loads();
        }
    }

    // epilogue: fp16 partial [ks][b][i][c]; C/D: col=lane&15, row=(lane>>4)*4+r
    unsigned short* p = part + (size_t)ks * PHALF_E;
    #pragma unroll
    for (int nf = 0; nf < 2; ++nf) {
        const int col = col0 + wn * 32 + nf * 16 + (lane & 15);
        const int bcol = col >> 4, c = col & 15;
        #pragma unroll
        for (int r = 0; r < 4; ++r) {
            const int row = row0 + wm * 16 + (lane >> 4) * 4 + r;
            p[bcol * (NN * CC) + row * CC + c] =
                (unsigned short)(pack_f16_2(acc[nf][r], 0.f) & 0xFFFFu);
        }
    }
    // fused copy (ks==0 blocks): 32x32 patch of inp -> out[:, :1024]
    if (ks == 0) {
        const int mr = row0 + (tid >> 3);
        const int c = blockIdx.x * 32 + (tid & 7) * 4;
        *(f32x4*)(out + mr * OUTW + c) = *(const f32x4*)(inp + mr * AA + c);
    }
}

// ---------------------------------------------------------------------------
// Kernel 2: pairwise exp(-L1), fp16-packed C dim, Jt=4.
// Grid (128 b, 4 jq) = 512 blocks, 256 threads. Staging: split-K sum with
// 8 packed v_pk_add_f16; LDS rows 32 B fp16, stride 48 B (16B-aligned).
// Thread (jg,q): 4 j's in regs, i = ii*16+q; 16-wide shfl reduce.
// ---------------------------------------------------------------------------
__global__ __launch_bounds__(256) void pair_kernel(const unsigned short* __restrict__ part,
                                                   float* __restrict__ out) {
    const int b = blockIdx.x;       // 0..127
    const int jq = blockIdx.y;      // 0..3
    const int tid = threadIdx.x;

    __shared__ __align__(16) char smem[NN * 48];   // 12 KiB

    const unsigned short* p0 = part + (size_t)b * (NN * CC);
    const unsigned short* p1 = p0 + PHALF_E;

    union U { u32x4 v; f16x2 h[4]; };

    {   // stage row i = tid: fp16 split-K sum, packed
        U x0a, x0b, x1a, x1b;
        x0a.v = *(const u32x4*)(p0 + tid * CC);
        x0b.v = *(const u32x4*)(p0 + tid * CC + 8);
        x1a.v = *(const u32x4*)(p1 + tid * CC);
        x1b.v = *(const u32x4*)(p1 + tid * CC + 8);
        U sa, sb;
        #pragma unroll
        for (int h = 0; h < 4; ++h) {
            sa.h[h] = x0a.h[h] + x1a.h[h];
            sb.h[h] = x0b.h[h] + x1b.h[h];
        }
        char* dst = smem + tid * 48;
        *(u32x4*)dst = sa.v;
        *(u32x4*)(dst + 16) = sb.v;
    }
    __syncthreads();

    const int jg = tid >> 4;     // 0..15
    const int q = tid & 15;      // 0..15
    const int j0 = jq * 64 + jg * 4;

    f16x2 ar[4][8];
    #pragma unroll
    for (int jj = 0; jj < 4; ++jj) {
        U ra, rb;
        ra.v = *(const u32x4*)(smem + (j0 + jj) * 48);
        rb.v = *(const u32x4*)(smem + (j0 + jj) * 48 + 16);
        #pragma unroll
        for (int h = 0; h < 4; ++h) { ar[jj][h] = ra.h[h]; ar[jj][4 + h] = rb.h[h]; }
    }

    float s[4] = {0.f, 0.f, 0.f, 0.f};
    #pragma unroll 4
    for (int ii = 0; ii < 16; ++ii) {
        const char* rp = smem + (ii * 16 + q) * 48;
        U ra, rb;
        ra.v = *(const u32x4*)rp;
        rb.v = *(const u32x4*)(rp + 16);
        f16x2 rv[8];
        #pragma unroll
        for (int h = 0; h < 4; ++h) { rv[h] = ra.h[h]; rv[4 + h] = rb.h[h]; }
        #pragma unroll
        for (int jj = 0; jj < 4; ++jj) {
            f16x2 d2 = { (_Float16)0.f, (_Float16)0.f };
            #pragma unroll
            for (int h = 0; h < 8; ++h) {
                union { f16x2 hh; unsigned u; } tt;
                tt.hh = rv[h] - ar[jj][h];
                tt.u &= 0x7FFF7FFFu;        // packed abs
                d2 += tt.hh;
            }
            const float d = (float)d2.x + (float)d2.y;
            s[jj] += __expf(-d);
        }
    }
    #pragma unroll
    for (int jj = 0; jj < 4; ++jj) {
        s[jj] += __shfl_xor(s[jj], 1);
        s[jj] += __shfl_xor(s[jj], 2);
        s[jj] += __shfl_xor(s[jj], 4);
        s[jj] += __shfl_xor(s[jj], 8);
    }
    if (q == 0) {
        #pragma unroll
        for (int jj = 0; jj < 4; ++jj)
            out[(j0 + jj) * OUTW + AA + b] = (s[jj] - 1.0f) * (1.0f / 255.0f);
    }
}

extern "C" void kernel_launch(void* const* d_in, const int* in_sizes, int n_in,
                              void* d_out, int out_size, void* d_ws, size_t ws_size,
                              hipStream_t stream) {
    const float* inp = (const float*)d_in[0];     // [256][1024]
    const float* theta = (const float*)d_in[1];   // [1024][2048]
    float* out = (float*)d_out;                   // [256][1152]
    unsigned short* part = (unsigned short*)d_ws; // 2 fp16 partials, 2 MiB

    gemm_kernel<<<dim3(32, 8, 2), 256, 0, stream>>>(inp, theta, part, out);
    pair_kernel<<<dim3(128, 4), 256, 0, stream>>>(part, out);
}

// Round 10
// 22.299 us; speedup vs baseline: 6.8998x; 1.0235x over previous
//
#include <hip/hip_runtime.h>

// N=256, A=1024, B=128, C=16
//   act = inp @ theta.reshape(1024, 2048)            (bf16 MFMA, split-K=4)
//   d[i,j,b] = sum_c |act[j,b,c] - act[i,b,c]|
//   mb[j,b]  = (sum_i exp(-d[i,j,b]) - 1) / 255
//   out = concat([inp, mb], axis=1)                  [256, 1152] fp32
//
// Two kernels (cooperative grid.sync measured at ~100 µs in r4/r8 — never).
// K1: pipelined bf16-MFMA GEMM, split-K=4, 1024 blocks (4/CU) -> bf16
//     partials part[ks][b][i][c].
// K2: pairwise exp(-L1), fp32 math (r6 form, best measured), 4-partial sum.

#define NN 256
#define AA 1024
#define CC 16
#define NBB 2048       // B*C
#define OUTW 1152      // A + B
#define PHALF_E (128 * 256 * 16)   // elements per split-K partial (bf16)

typedef __attribute__((ext_vector_type(4))) float f32x4;
typedef __attribute__((ext_vector_type(8))) short bf16x8;
typedef __attribute__((ext_vector_type(4))) unsigned int u32x4;
typedef __attribute__((ext_vector_type(8))) unsigned short u16x8;

// pack two fp32 -> two bf16 (truncation) in ONE v_perm_b32.
__device__ __forceinline__ unsigned int pack_bf2(float lo, float hi) {
    union { float f; unsigned u; } a, b;
    a.f = lo; b.f = hi;
    return __builtin_amdgcn_perm(b.u, a.u, 0x07060302u);
}

__device__ __forceinline__ unsigned short f2bf_trunc(float x) {
    union { float f; unsigned u; } v; v.f = x;
    return (unsigned short)(v.u >> 16);
}

__device__ __forceinline__ float bf2f(unsigned short h) {
    union { unsigned u; float f; } v; v.u = ((unsigned)h) << 16;
    return v.f;
}

// barrier that does NOT drain vmcnt (LDS visibility only) — prefetch global
// loads stay in flight across it.
__device__ __forceinline__ void barrier_keep_loads() {
    asm volatile("s_waitcnt lgkmcnt(0)" ::: "memory");
    __builtin_amdgcn_s_barrier();
    __builtin_amdgcn_sched_barrier(0);
}

// ---------------------------------------------------------------------------
// Kernel 1: bf16-MFMA GEMM, tile 32m x 64n, BK=64, split-K=4 (4 ktiles).
// Grid (32 bn, 8 bm, 4 ks) = 1024 blocks (4/CU, 4 waves/SIMD), 256 threads.
// Double-buffered LDS, one non-draining barrier per ktile, depth-2 register
// prefetch. LDS [m][k]/[n][k] bf16 rows 128 B, XOR swizzle byte^=(row&7)<<4.
// Output: bf16 partials part[ks][b][i][c] (b = col/16).
// ---------------------------------------------------------------------------
__global__ __launch_bounds__(256) void gemm_kernel(const float* __restrict__ inp,
                                                   const float* __restrict__ theta,
                                                   unsigned short* __restrict__ part,
                                                   float* __restrict__ out) {
    const int tid = threadIdx.x;
    const int lane = tid & 63;
    const int w = tid >> 6;
    const int wn = w & 1, wm = w >> 1;
    const int col0 = blockIdx.x * 64;
    const int row0 = blockIdx.y * 32;
    const int ks = blockIdx.z;
    const int kbase = ks * 256;

    __shared__ unsigned short As[2][32 * 64];   // 2 x 4 KiB  [m][k]
    __shared__ unsigned short Bs[2][64 * 64];   // 2 x 8 KiB  [n][k]

    const int am = tid >> 3, ach = tid & 7;     // A stage: row, 16B chunk
    const int nb = tid & 63, kq = tid >> 6;     // B stage: n row, k quarter

    const float* const abase = inp + (row0 + am) * AA + kbase + ach * 8;
    const float* const bbase = theta + (kbase + kq * 16) * NBB + col0 + nb;

    f32x4 a0[2], a1[2];
    float bv[2][16];

    #pragma unroll
    for (int s = 0; s < 2; ++s) {
        const float* asrc = abase + s * 64;
        a0[s] = *(const f32x4*)asrc; a1[s] = *(const f32x4*)(asrc + 4);
        const float* bsrc = bbase + (size_t)s * 64 * NBB;
        #pragma unroll
        for (int u = 0; u < 16; ++u) bv[s][u] = bsrc[u * NBB];
    }

    f32x4 acc[2] = {};

    #pragma unroll
    for (int kt = 0; kt < 4; ++kt) {
        if (kt == 0) {
            char* Asb = (char*)As[0]; char* Bsb = (char*)Bs[0];
            u32x4 ha;
            ha.x = pack_bf2(a0[0].x, a0[0].y); ha.y = pack_bf2(a0[0].z, a0[0].w);
            ha.z = pack_bf2(a1[0].x, a1[0].y); ha.w = pack_bf2(a1[0].z, a1[0].w);
            *(u32x4*)(Asb + ((am * 128 + ach * 16) ^ ((am & 7) << 4))) = ha;
            u32x4 hb0, hb1;
            hb0.x = pack_bf2(bv[0][0], bv[0][1]);   hb0.y = pack_bf2(bv[0][2], bv[0][3]);
            hb0.z = pack_bf2(bv[0][4], bv[0][5]);   hb0.w = pack_bf2(bv[0][6], bv[0][7]);
            hb1.x = pack_bf2(bv[0][8], bv[0][9]);   hb1.y = pack_bf2(bv[0][10], bv[0][11]);
            hb1.z = pack_bf2(bv[0][12], bv[0][13]); hb1.w = pack_bf2(bv[0][14], bv[0][15]);
            const int bb = nb * 128 + kq * 32, swz = (nb & 7) << 4;
            *(u32x4*)(Bsb + (bb ^ swz)) = hb0;
            *(u32x4*)(Bsb + ((bb + 16) ^ swz)) = hb1;
            barrier_keep_loads();
        }
        if (kt < 2) {
            const int s = kt & 1;
            const float* asrc = abase + (kt + 2) * 64;
            a0[s] = *(const f32x4*)asrc; a1[s] = *(const f32x4*)(asrc + 4);
            const float* bsrc = bbase + (size_t)(kt + 2) * 64 * NBB;
            #pragma unroll
            for (int u = 0; u < 16; ++u) bv[s][u] = bsrc[u * NBB];
        }
        {
            char* Asb = (char*)As[kt & 1]; char* Bsb = (char*)Bs[kt & 1];
            #pragma unroll
            for (int ks2 = 0; ks2 < 2; ++ks2) {
                const int kbyte = ks2 * 64 + (lane >> 4) * 16;
                const int m = wm * 16 + (lane & 15);
                const bf16x8 af = *(bf16x8*)(Asb + ((m * 128 + kbyte) ^ ((m & 7) << 4)));
                #pragma unroll
                for (int nf = 0; nf < 2; ++nf) {
                    const int n = wn * 32 + nf * 16 + (lane & 15);
                    const bf16x8 bfv = *(bf16x8*)(Bsb + ((n * 128 + kbyte) ^ ((n & 7) << 4)));
                    acc[nf] = __builtin_amdgcn_mfma_f32_16x16x32_bf16(af, bfv, acc[nf], 0, 0, 0);
                }
            }
        }
        if (kt < 3) {
            const int s = (kt + 1) & 1;
            char* Asb = (char*)As[s]; char* Bsb = (char*)Bs[s];
            u32x4 ha;
            ha.x = pack_bf2(a0[s].x, a0[s].y); ha.y = pack_bf2(a0[s].z, a0[s].w);
            ha.z = pack_bf2(a1[s].x, a1[s].y); ha.w = pack_bf2(a1[s].z, a1[s].w);
            *(u32x4*)(Asb + ((am * 128 + ach * 16) ^ ((am & 7) << 4))) = ha;
            u32x4 hb0, hb1;
            hb0.x = pack_bf2(bv[s][0], bv[s][1]);   hb0.y = pack_bf2(bv[s][2], bv[s][3]);
            hb0.z = pack_bf2(bv[s][4], bv[s][5]);   hb0.w = pack_bf2(bv[s][6], bv[s][7]);
            hb1.x = pack_bf2(bv[s][8], bv[s][9]);   hb1.y = pack_bf2(bv[s][10], bv[s][11]);
            hb1.z = pack_bf2(bv[s][12], bv[s][13]); hb1.w = pack_bf2(bv[s][14], bv[s][15]);
            const int bb = nb * 128 + kq * 32, swz = (nb & 7) << 4;
            *(u32x4*)(Bsb + (bb ^ swz)) = hb0;
            *(u32x4*)(Bsb + ((bb + 16) ^ swz)) = hb1;
            barrier_keep_loads();
        }
    }

    // epilogue: bf16 partial [ks][b][i][c]; C/D: col=lane&15, row=(lane>>4)*4+r
    unsigned short* p = part + (size_t)ks * PHALF_E;
    #pragma unroll
    for (int nf = 0; nf < 2; ++nf) {
        const int col = col0 + wn * 32 + nf * 16 + (lane & 15);
        const int bcol = col >> 4, c = col & 15;
        #pragma unroll
        for (int r = 0; r < 4; ++r) {
            const int row = row0 + wm * 16 + (lane >> 4) * 4 + r;
            p[bcol * (NN * CC) + row * CC + c] = f2bf_trunc(acc[nf][r]);
        }
    }
    // fused copy (ks==0 blocks): 32x32 patch of inp -> out[:, :1024]
    if (ks == 0) {
        const int mr = row0 + (tid >> 3);
        const int c = blockIdx.x * 32 + (tid & 7) * 4;
        *(f32x4*)(out + mr * OUTW + c) = *(const f32x4*)(inp + mr * AA + c);
    }
}

// ---------------------------------------------------------------------------
// Kernel 2: pairwise exp(-L1), fp32 math (r6 form), Jt=4, 4-partial sum.
// Grid (128 b, 4 jq) = 512 blocks, 256 threads. Thread tid stages row tid:
// 4 partials x 32 B coalesced, bf16->f32 sum into LDS rows padded to 20
// floats (2-way bank alias max). Inner: 4 j's in regs, i = ii*16 + q,
// 16-wide __shfl_xor reduce.
// ---------------------------------------------------------------------------
__global__ __launch_bounds__(256) void pair_kernel(const unsigned short* __restrict__ part,
                                                   float* __restrict__ out) {
    const int b = blockIdx.x;       // 0..127
    const int jq = blockIdx.y;      // 0..3
    const int tid = threadIdx.x;

    __shared__ float sA[NN * 20];   // 20 KiB

    const unsigned short* pb = part + (size_t)b * (NN * CC);

    {   // stage row i = tid: sum 4 bf16 partials -> fp32
        float acc[16];
        #pragma unroll
        for (int e = 0; e < 16; ++e) acc[e] = 0.f;
        #pragma unroll
        for (int t = 0; t < 4; ++t) {
            const u16x8 xa = *(const u16x8*)(pb + (size_t)t * PHALF_E + tid * CC);
            const u16x8 xb = *(const u16x8*)(pb + (size_t)t * PHALF_E + tid * CC + 8);
            #pragma unroll
            for (int e = 0; e < 8; ++e) {
                acc[e] += bf2f(xa[e]);
                acc[8 + e] += bf2f(xb[e]);
            }
        }
        float* dst = sA + tid * 20;
        #pragma unroll
        for (int e = 0; e < 16; ++e) dst[e] = acc[e];
    }
    __syncthreads();

    const int jg = tid >> 4;        // 0..15
    const int q = tid & 15;         // 0..15
    const int j0 = jq * 64 + jg * 4;

    float ar[4][16];
    #pragma unroll
    for (int jj = 0; jj < 4; ++jj)
        #pragma unroll
        for (int c = 0; c < 16; ++c)
            ar[jj][c] = sA[(j0 + jj) * 20 + c];

    float s[4] = {0.f, 0.f, 0.f, 0.f};
    #pragma unroll 4
    for (int ii = 0; ii < 16; ++ii) {
        const float* row = sA + (ii * 16 + q) * 20;
        float rv[16];
        #pragma unroll
        for (int c4 = 0; c4 < 4; ++c4)
            *(f32x4*)(rv + c4 * 4) = *(const f32x4*)(row + c4 * 4);
        #pragma unroll
        for (int jj = 0; jj < 4; ++jj) {
            float d = 0.f;
            #pragma unroll
            for (int c = 0; c < 16; ++c) d += fabsf(rv[c] - ar[jj][c]);
            s[jj] += __expf(-d);
        }
    }
    #pragma unroll
    for (int jj = 0; jj < 4; ++jj) {
        s[jj] += __shfl_xor(s[jj], 1);
        s[jj] += __shfl_xor(s[jj], 2);
        s[jj] += __shfl_xor(s[jj], 4);
        s[jj] += __shfl_xor(s[jj], 8);
    }
    if (q == 0) {
        #pragma unroll
        for (int jj = 0; jj < 4; ++jj)
            out[(j0 + jj) * OUTW + AA + b] = (s[jj] - 1.0f) * (1.0f / 255.0f);
    }
}

extern "C" void kernel_launch(void* const* d_in, const int* in_sizes, int n_in,
                              void* d_out, int out_size, void* d_ws, size_t ws_size,
                              hipStream_t stream) {
    const float* inp = (const float*)d_in[0];     // [256][1024]
    const float* theta = (const float*)d_in[1];   // [1024][2048]
    float* out = (float*)d_out;                   // [256][1152]
    unsigned short* part = (unsigned short*)d_ws; // 4 bf16 partials, 4 MiB

    gemm_kernel<<<dim3(32, 8, 4), 256, 0, stream>>>(inp, theta, part, out);
    pair_kernel<<<dim3(128, 4), 256, 0, stream>>>(part, out);
}

// Round 11
// 21.739 us; speedup vs baseline: 7.0775x; 1.0258x over previous
//
#include <hip/hip_runtime.h>

// N=256, A=1024, B=128, C=16
//   act = inp @ theta.reshape(1024, 2048)            (bf16 MFMA, split-K=2)
//   d[i,j,b] = sum_c |act[j,b,c] - act[i,b,c]|
//   mb[j,b]  = (sum_i exp(-d[i,j,b]) - 1) / 255
//   out = concat([inp, mb], axis=1)                  [256, 1152] fp32
//
// Best-measured configuration (round 6, 21.7 µs):
//   - two kernels; cooperative grid.sync measured ~100 µs on this platform
//     (r4: 256 blk, r8: 512 blk) — never fuse via grid sync here.
//   - K1: pipelined bf16-MFMA GEMM, split-K=2, depth-2 register prefetch,
//     one non-vmcnt-draining barrier per ktile, XOR-swizzled LDS.
//   - K2: pairwise exp(-L1), fp32 math, Jt=4 j-register blocking
//     (fp16-packed variant measured neutral-to-worse in r9).

#define NN 256
#define AA 1024
#define CC 16
#define NBB 2048       // B*C
#define OUTW 1152      // A + B
#define PHALF_E (128 * 256 * 16)   // elements per split-K partial (bf16, 1 MiB)

typedef __attribute__((ext_vector_type(4))) float f32x4;
typedef __attribute__((ext_vector_type(8))) short bf16x8;
typedef __attribute__((ext_vector_type(4))) unsigned int u32x4;
typedef __attribute__((ext_vector_type(8))) unsigned short u16x8;

// pack two fp32 -> two bf16 (truncation) in ONE v_perm_b32.
__device__ __forceinline__ unsigned int pack_bf2(float lo, float hi) {
    union { float f; unsigned u; } a, b;
    a.f = lo; b.f = hi;
    return __builtin_amdgcn_perm(b.u, a.u, 0x07060302u);
}

__device__ __forceinline__ unsigned short f2bf_trunc(float x) {
    union { float f; unsigned u; } v; v.f = x;
    return (unsigned short)(v.u >> 16);
}

__device__ __forceinline__ float bf2f(unsigned short h) {
    union { unsigned u; float f; } v; v.u = ((unsigned)h) << 16;
    return v.f;
}

// barrier that does NOT drain vmcnt (LDS visibility only) — prefetch global
// loads stay in flight across it.
__device__ __forceinline__ void barrier_keep_loads() {
    asm volatile("s_waitcnt lgkmcnt(0)" ::: "memory");
    __builtin_amdgcn_s_barrier();
    __builtin_amdgcn_sched_barrier(0);
}

// ---------------------------------------------------------------------------
// Kernel 1: bf16-MFMA GEMM, tile 32m x 64n, BK=64, split-K=2 (8 ktiles).
// Grid (32 bn, 8 bm, 2 ks) = 512 blocks (2/CU), 256 threads (4 waves, 2x2).
// Double-buffered LDS, one non-draining barrier per ktile, depth-2 register
// prefetch. LDS [m][k]/[n][k] bf16 rows 128 B, XOR swizzle byte^=(row&7)<<4.
// Output: bf16 partials part[ks][b][i][c] (b = col/16).
// ---------------------------------------------------------------------------
__global__ __launch_bounds__(256) void gemm_kernel(const float* __restrict__ inp,
                                                   const float* __restrict__ theta,
                                                   unsigned short* __restrict__ part,
                                                   float* __restrict__ out) {
    const int tid = threadIdx.x;
    const int lane = tid & 63;
    const int w = tid >> 6;
    const int wn = w & 1, wm = w >> 1;
    const int col0 = blockIdx.x * 64;
    const int row0 = blockIdx.y * 32;
    const int ks = blockIdx.z;
    const int kbase = ks * 512;

    __shared__ unsigned short As[2][32 * 64];   // 2 x 4 KiB  [m][k]
    __shared__ unsigned short Bs[2][64 * 64];   // 2 x 8 KiB  [n][k]

    const int am = tid >> 3, ach = tid & 7;     // A stage: row, 16B chunk
    const int nb = tid & 63, kq = tid >> 6;     // B stage: n row, k quarter

    const float* const abase = inp + (row0 + am) * AA + kbase + ach * 8;
    const float* const bbase = theta + (kbase + kq * 16) * NBB + col0 + nb;

    f32x4 a0[2], a1[2];
    float bv[2][16];

    #pragma unroll
    for (int s = 0; s < 2; ++s) {
        const float* asrc = abase + s * 64;
        a0[s] = *(const f32x4*)asrc; a1[s] = *(const f32x4*)(asrc + 4);
        const float* bsrc = bbase + (size_t)s * 64 * NBB;
        #pragma unroll
        for (int u = 0; u < 16; ++u) bv[s][u] = bsrc[u * NBB];
    }

    f32x4 acc[2] = {};

    #pragma unroll
    for (int kt = 0; kt < 8; ++kt) {
        if (kt == 0) {
            char* Asb = (char*)As[0]; char* Bsb = (char*)Bs[0];
            u32x4 ha;
            ha.x = pack_bf2(a0[0].x, a0[0].y); ha.y = pack_bf2(a0[0].z, a0[0].w);
            ha.z = pack_bf2(a1[0].x, a1[0].y); ha.w = pack_bf2(a1[0].z, a1[0].w);
            *(u32x4*)(Asb + ((am * 128 + ach * 16) ^ ((am & 7) << 4))) = ha;
            u32x4 hb0, hb1;
            hb0.x = pack_bf2(bv[0][0], bv[0][1]);   hb0.y = pack_bf2(bv[0][2], bv[0][3]);
            hb0.z = pack_bf2(bv[0][4], bv[0][5]);   hb0.w = pack_bf2(bv[0][6], bv[0][7]);
            hb1.x = pack_bf2(bv[0][8], bv[0][9]);   hb1.y = pack_bf2(bv[0][10], bv[0][11]);
            hb1.z = pack_bf2(bv[0][12], bv[0][13]); hb1.w = pack_bf2(bv[0][14], bv[0][15]);
            const int bb = nb * 128 + kq * 32, swz = (nb & 7) << 4;
            *(u32x4*)(Bsb + (bb ^ swz)) = hb0;
            *(u32x4*)(Bsb + ((bb + 16) ^ swz)) = hb1;
            barrier_keep_loads();
        }
        if (kt < 6) {
            const int s = kt & 1;
            const float* asrc = abase + (kt + 2) * 64;
            a0[s] = *(const f32x4*)asrc; a1[s] = *(const f32x4*)(asrc + 4);
            const float* bsrc = bbase + (size_t)(kt + 2) * 64 * NBB;
            #pragma unroll
            for (int u = 0; u < 16; ++u) bv[s][u] = bsrc[u * NBB];
        }
        {
            char* Asb = (char*)As[kt & 1]; char* Bsb = (char*)Bs[kt & 1];
            #pragma unroll
            for (int ks2 = 0; ks2 < 2; ++ks2) {
                const int kbyte = ks2 * 64 + (lane >> 4) * 16;
                const int m = wm * 16 + (lane & 15);
                const bf16x8 af = *(bf16x8*)(Asb + ((m * 128 + kbyte) ^ ((m & 7) << 4)));
                #pragma unroll
                for (int nf = 0; nf < 2; ++nf) {
                    const int n = wn * 32 + nf * 16 + (lane & 15);
                    const bf16x8 bfv = *(bf16x8*)(Bsb + ((n * 128 + kbyte) ^ ((n & 7) << 4)));
                    acc[nf] = __builtin_amdgcn_mfma_f32_16x16x32_bf16(af, bfv, acc[nf], 0, 0, 0);
                }
            }
        }
        if (kt < 7) {
            const int s = (kt + 1) & 1;
            char* Asb = (char*)As[s]; char* Bsb = (char*)Bs[s];
            u32x4 ha;
            ha.x = pack_bf2(a0[s].x, a0[s].y); ha.y = pack_bf2(a0[s].z, a0[s].w);
            ha.z = pack_bf2(a1[s].x, a1[s].y); ha.w = pack_bf2(a1[s].z, a1[s].w);
            *(u32x4*)(Asb + ((am * 128 + ach * 16) ^ ((am & 7) << 4))) = ha;
            u32x4 hb0, hb1;
            hb0.x = pack_bf2(bv[s][0], bv[s][1]);   hb0.y = pack_bf2(bv[s][2], bv[s][3]);
            hb0.z = pack_bf2(bv[s][4], bv[s][5]);   hb0.w = pack_bf2(bv[s][6], bv[s][7]);
            hb1.x = pack_bf2(bv[s][8], bv[s][9]);   hb1.y = pack_bf2(bv[s][10], bv[s][11]);
            hb1.z = pack_bf2(bv[s][12], bv[s][13]); hb1.w = pack_bf2(bv[s][14], bv[s][15]);
            const int bb = nb * 128 + kq * 32, swz = (nb & 7) << 4;
            *(u32x4*)(Bsb + (bb ^ swz)) = hb0;
            *(u32x4*)(Bsb + ((bb + 16) ^ swz)) = hb1;
            barrier_keep_loads();
        }
    }

    // epilogue: bf16 partial [ks][b][i][c]; C/D: col=lane&15, row=(lane>>4)*4+r
    unsigned short* p = part + (size_t)ks * PHALF_E;
    #pragma unroll
    for (int nf = 0; nf < 2; ++nf) {
        const int col = col0 + wn * 32 + nf * 16 + (lane & 15);
        const int bcol = col >> 4, c = col & 15;
        #pragma unroll
        for (int r = 0; r < 4; ++r) {
            const int row = row0 + wm * 16 + (lane >> 4) * 4 + r;
            p[bcol * (NN * CC) + row * CC + c] = f2bf_trunc(acc[nf][r]);
        }
    }
    // fused copy (ks==0 only): 32x32 patch of inp -> out[:, :1024]
    if (ks == 0) {
        const int mr = row0 + (tid >> 3);
        const int c = blockIdx.x * 32 + (tid & 7) * 4;
        *(f32x4*)(out + mr * OUTW + c) = *(const f32x4*)(inp + mr * AA + c);
    }
}

// ---------------------------------------------------------------------------
// Kernel 2: pairwise exp(-L1), Jt=4, bf16 split-K partial sum in staging.
// Grid (128 b, 4 jq) = 512 blocks, 256 threads. Each thread stages one row
// (16 bf16 from each partial = 2x16B coalesced), converts+sums to fp32 LDS
// rows padded to 20 floats. Inner loop: 4 j's in registers, i = ii*16 + q.
// ---------------------------------------------------------------------------
__global__ __launch_bounds__(256) void pair_kernel(const unsigned short* __restrict__ part,
                                                   float* __restrict__ out) {
    const int b = blockIdx.x;       // 0..127
    const int jq = blockIdx.y;      // 0..3
    const int tid = threadIdx.x;

    __shared__ float sA[NN * 20];   // 20 KiB

    const unsigned short* p0 = part + (size_t)b * (NN * CC);
    const unsigned short* p1 = p0 + PHALF_E;

    {   // thread tid stages row i = tid
        const u16x8 x0a = *(const u16x8*)(p0 + tid * CC);
        const u16x8 x0b = *(const u16x8*)(p0 + tid * CC + 8);
        const u16x8 x1a = *(const u16x8*)(p1 + tid * CC);
        const u16x8 x1b = *(const u16x8*)(p1 + tid * CC + 8);
        float* dst = sA + tid * 20;
        #pragma unroll
        for (int e = 0; e < 8; ++e) dst[e] = bf2f(x0a[e]) + bf2f(x1a[e]);
        #pragma unroll
        for (int e = 0; e < 8; ++e) dst[8 + e] = bf2f(x0b[e]) + bf2f(x1b[e]);
    }
    __syncthreads();

    const int jg = tid >> 4;        // 0..15
    const int q = tid & 15;         // 0..15
    const int j0 = jq * 64 + jg * 4;

    float ar[4][16];
    #pragma unroll
    for (int jj = 0; jj < 4; ++jj)
        #pragma unroll
        for (int c = 0; c < 16; ++c)
            ar[jj][c] = sA[(j0 + jj) * 20 + c];

    float s[4] = {0.f, 0.f, 0.f, 0.f};
    #pragma unroll 4
    for (int ii = 0; ii < 16; ++ii) {
        const float* row = sA + (ii * 16 + q) * 20;
        float rv[16];
        #pragma unroll
        for (int c4 = 0; c4 < 4; ++c4)
            *(f32x4*)(rv + c4 * 4) = *(const f32x4*)(row + c4 * 4);
        #pragma unroll
        for (int jj = 0; jj < 4; ++jj) {
            float d = 0.f;
            #pragma unroll
            for (int c = 0; c < 16; ++c) d += fabsf(rv[c] - ar[jj][c]);
            s[jj] += __expf(-d);
        }
    }
    #pragma unroll
    for (int jj = 0; jj < 4; ++jj) {
        s[jj] += __shfl_xor(s[jj], 1);
        s[jj] += __shfl_xor(s[jj], 2);
        s[jj] += __shfl_xor(s[jj], 4);
        s[jj] += __shfl_xor(s[jj], 8);
    }
    if (q == 0) {
        #pragma unroll
        for (int jj = 0; jj < 4; ++jj)
            out[(j0 + jj) * OUTW + AA + b] = (s[jj] - 1.0f) * (1.0f / 255.0f);
    }
}

extern "C" void kernel_launch(void* const* d_in, const int* in_sizes, int n_in,
                              void* d_out, int out_size, void* d_ws, size_t ws_size,
                              hipStream_t stream) {
    const float* inp = (const float*)d_in[0];     // [256][1024]
    const float* theta = (const float*)d_in[1];   // [1024][2048]
    float* out = (float*)d_out;                   // [256][1152]
    unsigned short* part = (unsigned short*)d_ws; // 2 bf16 partials, 2 MiB

    gemm_kernel<<<dim3(32, 8, 2), 256, 0, stream>>>(inp, theta, part, out);
    pair_kernel<<<dim3(128, 4), 256, 0, stream>>>(part, out);
}